// Round 3
// baseline (131.904 us; speedup 1.0000x reference)
//
#include <hip/hip_runtime.h>

#define B 4
#define N 2048      // N1 == N2
#define F 256
#define O 256
#define LOG2E 1.4426950408889634f
#define NEG_BIG -9000000000000000.0f

typedef _Float16 f16;
typedef f16 f16x4 __attribute__((ext_vector_type(4)));
typedef f16 f16x8 __attribute__((ext_vector_type(8)));
typedef float f32x4 __attribute__((ext_vector_type(4)));

// ws float-index layout
#define WS_V1 0
#define WS_V2 256
#define WS_T1 512              // t1 * LOG2E  per (b,n2)
#define WS_T2 (512 + B*N)     // t2 (unscaled) per (b,n2)
// byte offsets in d_ws
#define WT_OFF (1u << 20)      // wordT: f16 [B][ft(16)][kc(64)][lane(64)][8] (4 MB)

__device__ __forceinline__ float alpha_of(float pre2) {
  return __builtin_amdgcn_exp2f(fmaxf(pre2, 0.2f * pre2));
}

// ---------------- kernel 1: v1 = W1 @ w3a, v2 = W2 @ w3b ----------------
__global__ __launch_bounds__(256) void k_v(const float* __restrict__ W1,
                                           const float* __restrict__ W2,
                                           const float* __restrict__ w3,
                                           float* __restrict__ ws) {
  int tid = threadIdx.x;
  int lane = tid & 63;
  int f = blockIdx.x * 4 + (tid >> 6);
  float a = 0.f, b = 0.f;
  #pragma unroll
  for (int k = 0; k < 4; ++k) {
    int o = lane + 64 * k;
    a += W1[f * O + o] * w3[o];
    b += W2[f * O + o] * w3[O + o];
  }
  #pragma unroll
  for (int off = 32; off > 0; off >>= 1) {
    a += __shfl_down(a, off);
    b += __shfl_down(b, off);
  }
  if (lane == 0) {
    ws[WS_V1 + f] = a;
    ws[WS_V2 + f] = b;
  }
}

// ---------------- kernel 2: k_prep = t1/t2 dots + f16 transpose -------------
// wordT layout for 16x16x32 B-frag: [b][ft(16)][kc(64)][lane(64)][8]
// where f = ft*16 + (l&15), k = kc*32 + (l>>4)*8 + j.
__global__ __launch_bounds__(256) void k_prep(const float* __restrict__ word,
                                              float* __restrict__ ws,
                                              f16* __restrict__ wordT) {
  __shared__ float v1s[F], v2s[F];
  __shared__ __align__(16) f16 tile[F][40];   // [f][r]
  int t = threadIdx.x;
  int k0 = blockIdx.x * 32;
  int b = blockIdx.y;

  if (t < 64)       ((float4*)v1s)[t]      = ((const float4*)(ws + WS_V1))[t];
  else if (t < 128) ((float4*)v2s)[t - 64] = ((const float4*)(ws + WS_V2))[t - 64];
  __syncthreads();

  int r = t >> 3;        // 0..31
  int cg = t & 7;
  const float* wrow = word + ((size_t)(b * N + k0 + r)) * F;
  float a = 0.f, bb = 0.f;
  #pragma unroll
  for (int i = 0; i < 8; ++i) {
    int c = i * 32 + cg * 4;
    float4 w = *(const float4*)(wrow + c);
    float4 x1 = *(const float4*)(v1s + c);
    float4 x2 = *(const float4*)(v2s + c);
    a  += w.x * x1.x + w.y * x1.y + w.z * x1.z + w.w * x1.w;
    bb += w.x * x2.x + w.y * x2.y + w.z * x2.z + w.w * x2.w;
    tile[c + 0][r] = (f16)w.x;
    tile[c + 1][r] = (f16)w.y;
    tile[c + 2][r] = (f16)w.z;
    tile[c + 3][r] = (f16)w.w;
  }
  #pragma unroll
  for (int off = 4; off > 0; off >>= 1) {
    a  += __shfl_down(a, off);
    bb += __shfl_down(bb, off);
  }
  if (cg == 0) {
    ws[WS_T1 + b * N + k0 + r] = a * LOG2E;
    ws[WS_T2 + b * N + k0 + r] = bb;
  }
  __syncthreads();

  // this block covers exactly one kc (= k0/32)
  size_t base = (size_t)b * F * N;
  int kc = k0 >> 5;
  #pragma unroll
  for (int s = 0; s < 4; ++s) {
    int u = t + 256 * s;
    int ft = u >> 6, l2 = u & 63;
    f16x8 h = *(const f16x8*)&tile[ft * 16 + (l2 & 15)][(l2 >> 4) * 8];
    *(f16x8*)(wordT + base + ((size_t)(ft * 64 + kc) * 64 + l2) * 8) = h;
  }
}

// ---------------- kernel 3: fused stats + softmax weights + MFMA GEMM --------
// 512 blocks x 512 thr (8 waves), 80KB LDS -> 2 blocks/CU (phase overlap across
// co-resident blocks). Block owns 16 rows x 256 cols.
// Phase A: wave w rows {2w, 2w+1}; per-lane k = i*256 + l*4 (conflict-free);
//   final f16 weights -> LDS [16][2048] with XOR swizzle byte ^= (row&7)<<4.
// Phase B: wave w = cols [32w,32w+32); 64 x {1 ds_read A-frag, 2 global B-frags,
//   2 x mfma_f32_16x16x32_f16}.
__global__ __launch_bounds__(512, 4) void k_sg(const float* __restrict__ adj,
                                               const float* __restrict__ ws,
                                               const f16* __restrict__ wordT,
                                               float* __restrict__ out) {
  extern __shared__ __align__(16) char smem[];        // 81920 B
  float* t1S = (float*)(smem + 65536);                // 8KB
  float* t2S = (float*)(smem + 73728);                // 8KB

  const int t = threadIdx.x;
  const int wv = t >> 6, l = t & 63;
  const int bid = blockIdx.x;
  const int sbid = (bid & 7) * 64 + (bid >> 3);       // XCD-chunked (512%8==0)
  const int row0 = sbid * 16;
  const int b = row0 >> 11;

  // stage t1/t2 (shared across the block's 16 rows)
  *(float4*)(t1S + t * 4) = *(const float4*)(ws + WS_T1 + b * N + t * 4);
  *(float4*)(t2S + t * 4) = *(const float4*)(ws + WS_T2 + b * N + t * 4);
  __syncthreads();

  // ---------------- Phase A ----------------
  #pragma unroll 1
  for (int rr = 0; rr < 2; ++rr) {
    const int lrow = wv * 2 + rr;                     // 0..15
    const float* arow = adj + (size_t)(row0 + lrow) * N;

    float deg = 0.f, dot = 0.f;
    unsigned mb = 0u;
    #pragma unroll
    for (int i = 0; i < 8; ++i) {
      int k = i * 256 + l * 4;
      float4 av = *(const float4*)(arow + k);
      float4 uv = *(const float4*)(t2S + k);
      deg += av.x + av.y + av.z + av.w;
      dot += av.x * uv.x + av.y * uv.y + av.z * uv.z + av.w * uv.w;
      mb |= (av.x > 0.f ? (1u << (4 * i + 0)) : 0u) |
            (av.y > 0.f ? (1u << (4 * i + 1)) : 0u) |
            (av.z > 0.f ? (1u << (4 * i + 2)) : 0u) |
            (av.w > 0.f ? (1u << (4 * i + 3)) : 0u);
    }
    #pragma unroll
    for (int off = 32; off > 0; off >>= 1) {
      deg += __shfl_xor(deg, off);
      dot += __shfl_xor(dot, off);
    }
    float degc = deg > 0.f ? deg : 1.f;
    float s2p = (dot / degc) * LOG2E;

    // alphas + row max
    float al[32];
    float m = NEG_BIG;
    #pragma unroll
    for (int i = 0; i < 8; ++i) {
      int k = i * 256 + l * 4;
      float4 pv = *(const float4*)(t1S + k);
      const float p[4] = {pv.x, pv.y, pv.z, pv.w};
      #pragma unroll
      for (int c = 0; c < 4; ++c) {
        int j = 4 * i + c;
        al[j] = ((mb >> j) & 1u) ? alpha_of(p[c] + s2p) : NEG_BIG;
        m = fmaxf(m, al[j]);
      }
    }
    #pragma unroll
    for (int off = 32; off > 0; off >>= 1) m = fmaxf(m, __shfl_xor(m, off));

    // z-terms in place -> weight = zterm * (1/Z)
    float negmL = -m * LOG2E;
    float z = 0.f;
    #pragma unroll
    for (int j = 0; j < 32; ++j) {
      float e = __builtin_amdgcn_exp2f(fmaf(al[j], LOG2E, negmL));
      z += e;
      al[j] = e;
    }
    #pragma unroll
    for (int off = 32; off > 0; off >>= 1) z += __shfl_xor(z, off);
    float sc, wn;
    if (deg > 0.f) { sc = 1.0f / z; wn = 0.f; }
    else           { sc = 0.f;      wn = 1.0f / (float)N; }

    // f16 weights -> LDS [16][2048], natural [row][k], XOR-swizzled
    #pragma unroll
    for (int i = 0; i < 8; ++i) {
      f16x4 h;
      #pragma unroll
      for (int c = 0; c < 4; ++c) {
        int j = 4 * i + c;
        float w = ((mb >> j) & 1u) ? al[j] * sc : wn;
        h[c] = (f16)w;
      }
      unsigned byteoff = (unsigned)(lrow * 4096 + i * 512 + l * 8) ^ ((unsigned)(lrow & 7) << 4);
      *(f16x4*)(smem + byteoff) = h;
    }
  }
  __syncthreads();

  // ---------------- Phase B ----------------
  const int ft0 = wv * 2;                             // wave covers ft0, ft0+1
  const unsigned abase = (unsigned)((l & 15) * 4096 + (l >> 4) * 16);
  const unsigned ax = ((unsigned)(l & 7)) << 4;
  const f16* bp0 = wordT + (size_t)b * (F * N) + ((size_t)ft0 * 64 * 64 + (size_t)l) * 8;
  const f16* bp1 = bp0 + (size_t)64 * 512;

  f32x4 acc0 = {0.f, 0.f, 0.f, 0.f};
  f32x4 acc1 = {0.f, 0.f, 0.f, 0.f};
  #pragma unroll 8
  for (int kc = 0; kc < 64; ++kc) {
    f16x8 af = *(const f16x8*)(smem + ((abase + kc * 64) ^ ax));
    f16x8 bf0 = *(const f16x8*)(bp0 + (size_t)kc * 512);
    f16x8 bf1 = *(const f16x8*)(bp1 + (size_t)kc * 512);
    acc0 = __builtin_amdgcn_mfma_f32_16x16x32_f16(af, bf0, acc0, 0, 0, 0);
    acc1 = __builtin_amdgcn_mfma_f32_16x16x32_f16(af, bf1, acc1, 0, 0, 0);
  }

  // C layout (16x16): col = lane&15, row = (lane>>4)*4 + reg
  const int orow = row0 + (l >> 4) * 4;
  const int c0 = ft0 * 16 + (l & 15);
  #pragma unroll
  for (int reg = 0; reg < 4; ++reg) {
    out[(size_t)(orow + reg) * F + c0]      = acc0[reg];
    out[(size_t)(orow + reg) * F + c0 + 16] = acc1[reg];
  }
}

extern "C" void kernel_launch(void* const* d_in, const int* in_sizes, int n_in,
                              void* d_out, int out_size, void* d_ws, size_t ws_size,
                              hipStream_t stream) {
  const float* word = (const float*)d_in[0];
  const float* adj  = (const float*)d_in[1];
  const float* W1   = (const float*)d_in[2];
  const float* W2   = (const float*)d_in[3];
  const float* w3   = (const float*)d_in[4];
  float* out = (float*)d_out;
  float* ws  = (float*)d_ws;
  f16* wordT = (f16*)((char*)d_ws + WT_OFF);

  static bool s_attr = false;
  if (!s_attr) {
    hipFuncSetAttribute((const void*)k_sg, hipFuncAttributeMaxDynamicSharedMemorySize, 81920);
    s_attr = true;
  }

  k_v<<<64, 256, 0, stream>>>(W1, W2, w3, ws);
  k_prep<<<dim3(N / 32, B), 256, 0, stream>>>(word, ws, wordT);
  k_sg<<<(B * N) / 16, 512, 81920, stream>>>(adj, ws, wordT, out);
}

// Round 5
// 130.462 us; speedup vs baseline: 1.0111x; 1.0111x over previous
//
#include <hip/hip_runtime.h>

#define B 4
#define N 2048      // N1 == N2
#define F 256
#define O 256
#define LOG2E 1.4426950408889634f
#define NEG_BIG -9000000000000000.0f

typedef _Float16 f16;
typedef f16 f16x4 __attribute__((ext_vector_type(4)));
typedef f16 f16x8 __attribute__((ext_vector_type(8)));
typedef float f32x4 __attribute__((ext_vector_type(4)));

// ws float-index layout
#define WS_V1 0
#define WS_V2 256
#define WS_T1 512              // t1 * LOG2E  per (b,n2)
#define WS_T2 (512 + B*N)     // t2 (unscaled) per (b,n2)
// byte offsets in d_ws
#define WT_OFF (1u << 20)      // wordT: f16 [B][ft(16)][kc(64)][lane(64)][8] (4 MB)
#define MK_OFF (6u << 20)      // mask:  u32 [row(8192)][lane(64)] (2 MB)

__device__ __forceinline__ float alpha_of(float pre2) {
  return __builtin_amdgcn_exp2f(fmaxf(pre2, 0.2f * pre2));
}

// ---------------- kernel 0: adj -> packed bitmask (pure HBM stream) ---------
// bit j (=4i+c) of word[row][l] = adj[row][i*256 + l*4 + c] > 0
__global__ __launch_bounds__(256) void k_mask(const float* __restrict__ adj,
                                              unsigned* __restrict__ maskg) {
  int t = threadIdx.x;
  int wv = t >> 6, l = t & 63;
  int row = blockIdx.x * 4 + wv;
  const float* arow = adj + (size_t)row * N;
  unsigned mb = 0u;
  #pragma unroll
  for (int i = 0; i < 8; ++i) {
    float4 av = *(const float4*)(arow + i * 256 + l * 4);
    mb |= (av.x > 0.f ? (1u << (4 * i + 0)) : 0u) |
          (av.y > 0.f ? (1u << (4 * i + 1)) : 0u) |
          (av.z > 0.f ? (1u << (4 * i + 2)) : 0u) |
          (av.w > 0.f ? (1u << (4 * i + 3)) : 0u);
  }
  maskg[(size_t)row * 64 + l] = mb;
}

// ---------------- kernel 1: v1 = W1 @ w3a, v2 = W2 @ w3b ----------------
__global__ __launch_bounds__(256) void k_v(const float* __restrict__ W1,
                                           const float* __restrict__ W2,
                                           const float* __restrict__ w3,
                                           float* __restrict__ ws) {
  int tid = threadIdx.x;
  int lane = tid & 63;
  int f = blockIdx.x * 4 + (tid >> 6);
  float a = 0.f, b = 0.f;
  #pragma unroll
  for (int k = 0; k < 4; ++k) {
    int o = lane + 64 * k;
    a += W1[f * O + o] * w3[o];
    b += W2[f * O + o] * w3[O + o];
  }
  #pragma unroll
  for (int off = 32; off > 0; off >>= 1) {
    a += __shfl_down(a, off);
    b += __shfl_down(b, off);
  }
  if (lane == 0) {
    ws[WS_V1 + f] = a;
    ws[WS_V2 + f] = b;
  }
}

// ---------------- kernel 2: k_prep = t1/t2 dots + f16 transpose -------------
// wordT layout for 16x16x32 B-frag: [b][ft(16)][kc(64)][lane(64)][8]
// where f = ft*16 + (l&15), k = kc*32 + (l>>4)*8 + j.
__global__ __launch_bounds__(256) void k_prep(const float* __restrict__ word,
                                              float* __restrict__ ws,
                                              f16* __restrict__ wordT) {
  __shared__ float v1s[F], v2s[F];
  __shared__ __align__(16) f16 tile[F][40];   // [f][r]
  int t = threadIdx.x;
  int k0 = blockIdx.x * 32;
  int b = blockIdx.y;

  if (t < 64)       ((float4*)v1s)[t]      = ((const float4*)(ws + WS_V1))[t];
  else if (t < 128) ((float4*)v2s)[t - 64] = ((const float4*)(ws + WS_V2))[t - 64];
  __syncthreads();

  int r = t >> 3;        // 0..31
  int cg = t & 7;
  const float* wrow = word + ((size_t)(b * N + k0 + r)) * F;
  float a = 0.f, bb = 0.f;
  #pragma unroll
  for (int i = 0; i < 8; ++i) {
    int c = i * 32 + cg * 4;
    float4 w = *(const float4*)(wrow + c);
    float4 x1 = *(const float4*)(v1s + c);
    float4 x2 = *(const float4*)(v2s + c);
    a  += w.x * x1.x + w.y * x1.y + w.z * x1.z + w.w * x1.w;
    bb += w.x * x2.x + w.y * x2.y + w.z * x2.z + w.w * x2.w;
    tile[c + 0][r] = (f16)w.x;
    tile[c + 1][r] = (f16)w.y;
    tile[c + 2][r] = (f16)w.z;
    tile[c + 3][r] = (f16)w.w;
  }
  #pragma unroll
  for (int off = 4; off > 0; off >>= 1) {
    a  += __shfl_down(a, off);
    bb += __shfl_down(bb, off);
  }
  if (cg == 0) {
    ws[WS_T1 + b * N + k0 + r] = a * LOG2E;
    ws[WS_T2 + b * N + k0 + r] = bb;
  }
  __syncthreads();

  // this block covers exactly one kc (= k0/32)
  size_t base = (size_t)b * F * N;
  int kc = k0 >> 5;
  #pragma unroll
  for (int s = 0; s < 4; ++s) {
    int u = t + 256 * s;
    int ft = u >> 6, l2 = u & 63;
    f16x8 h = *(const f16x8*)&tile[ft * 16 + (l2 & 15)][(l2 >> 4) * 8];
    *(f16x8*)(wordT + base + ((size_t)(ft * 64 + kc) * 64 + l2) * 8) = h;
  }
}

// ---------------- kernel 3: fused softmax weights + MFMA GEMM ---------------
// 256 blocks x 1024 thr (16 waves), 144KB LDS -> 1 block/CU, 4 waves/SIMD.
// Block owns 32 rows x 256 cols (L2: 256 blocks x 1MB wordT = 256MB).
// Phase A: wave w rows {2w,2w+1} from bitmask (no adj): deg=popcount,
//   dot=masked sum of t2S; weights -> LDS [32][2048] f16, XOR swz (row&7)<<4.
// Phase B: wave w = 16-col ftile w; 64 x {2 ds_read A-frags (rows +0/+16),
//   1 global B-frag, 2 x mfma_f32_16x16x32_f16}.
__global__ __launch_bounds__(1024, 4) void k_sg(const unsigned* __restrict__ maskg,
                                                const float* __restrict__ ws,
                                                const f16* __restrict__ wordT,
                                                float* __restrict__ out) {
  extern __shared__ __align__(16) char smem[];        // 147456 B
  float* t1S = (float*)(smem + 131072);               // 8KB
  float* t2S = (float*)(smem + 139264);               // 8KB

  const int t = threadIdx.x;
  const int wv = t >> 6, l = t & 63;
  const int bid = blockIdx.x;
  const int sbid = (bid & 7) * 32 + (bid >> 3);       // XCD-chunked (256%8==0)
  const int row0 = sbid * 32;
  const int b = row0 >> 11;

  // stage t1/t2 (shared across the block's 32 rows)
  if (t < 512) {
    *(float4*)(t1S + t * 4) = *(const float4*)(ws + WS_T1 + b * N + t * 4);
  } else {
    int u = t - 512;
    *(float4*)(t2S + u * 4) = *(const float4*)(ws + WS_T2 + b * N + u * 4);
  }
  __syncthreads();

  // ---------------- Phase A ----------------
  #pragma unroll 1
  for (int rr = 0; rr < 2; ++rr) {
    const int lrow = wv * 2 + rr;                     // 0..31
    const unsigned mb = maskg[(size_t)(row0 + lrow) * 64 + l];

    float deg = (float)__builtin_popcount(mb);
    float dot = 0.f;
    #pragma unroll
    for (int i = 0; i < 8; ++i) {
      float4 uv = *(const float4*)(t2S + i * 256 + l * 4);
      dot += (((mb >> (4 * i + 0)) & 1u) ? uv.x : 0.f);
      dot += (((mb >> (4 * i + 1)) & 1u) ? uv.y : 0.f);
      dot += (((mb >> (4 * i + 2)) & 1u) ? uv.z : 0.f);
      dot += (((mb >> (4 * i + 3)) & 1u) ? uv.w : 0.f);
    }
    #pragma unroll
    for (int off = 32; off > 0; off >>= 1) {
      deg += __shfl_xor(deg, off);
      dot += __shfl_xor(dot, off);
    }
    float degc = deg > 0.f ? deg : 1.f;
    float s2p = (dot / degc) * LOG2E;

    // alphas + row max
    float al[32];
    float m = NEG_BIG;
    #pragma unroll
    for (int i = 0; i < 8; ++i) {
      float4 pv = *(const float4*)(t1S + i * 256 + l * 4);
      const float p[4] = {pv.x, pv.y, pv.z, pv.w};
      #pragma unroll
      for (int c = 0; c < 4; ++c) {
        int j = 4 * i + c;
        al[j] = ((mb >> j) & 1u) ? alpha_of(p[c] + s2p) : NEG_BIG;
        m = fmaxf(m, al[j]);
      }
    }
    #pragma unroll
    for (int off = 32; off > 0; off >>= 1) m = fmaxf(m, __shfl_xor(m, off));

    // z-terms in place -> weight = zterm * (1/Z)
    float negmL = -m * LOG2E;
    float z = 0.f;
    #pragma unroll
    for (int j = 0; j < 32; ++j) {
      float e = __builtin_amdgcn_exp2f(fmaf(al[j], LOG2E, negmL));
      z += e;
      al[j] = e;
    }
    #pragma unroll
    for (int off = 32; off > 0; off >>= 1) z += __shfl_xor(z, off);
    float sc, wn;
    if (deg > 0.f) { sc = 1.0f / z; wn = 0.f; }
    else           { sc = 0.f;      wn = 1.0f / (float)N; }

    // f16 weights -> LDS [32][2048], natural [row][k], XOR-swizzled
    #pragma unroll
    for (int i = 0; i < 8; ++i) {
      f16x4 h;
      #pragma unroll
      for (int c = 0; c < 4; ++c) {
        int j = 4 * i + c;
        float w = ((mb >> j) & 1u) ? al[j] * sc : wn;
        h[c] = (f16)w;
      }
      unsigned byteoff = (unsigned)(lrow * 4096 + i * 512 + l * 8) ^ ((unsigned)(lrow & 7) << 4);
      *(f16x4*)(smem + byteoff) = h;
    }
  }
  __syncthreads();

  // ---------------- Phase B ----------------
  const int ftile = wv;                               // 0..15
  const unsigned abase = (unsigned)((l & 15) * 4096 + (l >> 4) * 16);
  const unsigned ax = ((unsigned)(l & 7)) << 4;       // (row&7)<<4, same for row+16
  const f16* bp = wordT + (size_t)b * (F * N) + ((size_t)ftile * 64 * 64 + (size_t)l) * 8;

  f32x4 acc0 = {0.f, 0.f, 0.f, 0.f};
  f32x4 acc1 = {0.f, 0.f, 0.f, 0.f};
  #pragma unroll 8
  for (int kc = 0; kc < 64; ++kc) {
    f16x8 bf = *(const f16x8*)(bp + (size_t)kc * 512);
    f16x8 a0 = *(const f16x8*)(smem + ((abase + kc * 64) ^ ax));
    f16x8 a1 = *(const f16x8*)(smem + ((abase + 16 * 4096 + kc * 64) ^ ax));
    acc0 = __builtin_amdgcn_mfma_f32_16x16x32_f16(a0, bf, acc0, 0, 0, 0);
    acc1 = __builtin_amdgcn_mfma_f32_16x16x32_f16(a1, bf, acc1, 0, 0, 0);
  }

  // C layout (16x16): col = lane&15, row = (lane>>4)*4 + reg
  const int orow = row0 + (l >> 4) * 4;
  const int c0 = ftile * 16 + (l & 15);
  #pragma unroll
  for (int reg = 0; reg < 4; ++reg) {
    out[(size_t)(orow + reg) * F + c0]      = acc0[reg];
    out[(size_t)(orow + 16 + reg) * F + c0] = acc1[reg];
  }
}

extern "C" void kernel_launch(void* const* d_in, const int* in_sizes, int n_in,
                              void* d_out, int out_size, void* d_ws, size_t ws_size,
                              hipStream_t stream) {
  const float* word = (const float*)d_in[0];
  const float* adj  = (const float*)d_in[1];
  const float* W1   = (const float*)d_in[2];
  const float* W2   = (const float*)d_in[3];
  const float* w3   = (const float*)d_in[4];
  float* out = (float*)d_out;
  float* ws  = (float*)d_ws;
  f16* wordT = (f16*)((char*)d_ws + WT_OFF);
  unsigned* maskg = (unsigned*)((char*)d_ws + MK_OFF);

  static bool s_attr = false;
  if (!s_attr) {
    hipFuncSetAttribute((const void*)k_sg, hipFuncAttributeMaxDynamicSharedMemorySize, 147456);
    s_attr = true;
  }

  k_mask<<<(B * N) / 4, 256, 0, stream>>>(adj, maskg);
  k_v<<<64, 256, 0, stream>>>(W1, W2, w3, ws);
  k_prep<<<dim3(N / 32, B), 256, 0, stream>>>(word, ws, wordT);
  k_sg<<<(B * N) / 32, 1024, 147456, stream>>>(maskg, ws, wordT, out);
}